// Round 1
// baseline (609.590 us; speedup 1.0000x reference)
//
#include <hip/hip_runtime.h>
#include <hip/hip_bf16.h>

// CFConv fused kernel, round 0.
//   out = segment_sum( (x@Wl+bl)[col] * (relu(rbf@W1+b1)@W2+b2), row )
// Strategy: bf16 MFMA (32x32x16) for all GEMMs; W1/W2 fragments register-resident
// (tile-invariant); per-tile rbf staging; atomicAdd scatter (measure this round).

#define N_NODES 40000
#define N_EDGES 640000
#define IN_CH 128
#define OUT_CH 128
#define NUM_RBF 64

#define TILE_M 64
#define NTILES (N_EDGES / TILE_M)  // 10000 exactly
#define RBF_STR 72                 // 64 + 8 pad (keeps 16B align, 2-way banks)
#define T_STR 136                  // 128 + 8 pad
#define W1_STR 72
#define W2_STR 136

typedef __attribute__((ext_vector_type(8))) short bf16x8;
typedef __attribute__((ext_vector_type(16))) float f32x16;

__device__ __forceinline__ unsigned short f2bf(float f) {
  // RNE f32 -> bf16 (inputs are finite/normal)
  unsigned u = __float_as_uint(f);
  unsigned r = (u + 0x7FFFu + ((u >> 16) & 1u)) >> 16;
  return (unsigned short)r;
}

// ---------------------------------------------------------------------------
// h = x @ Wl + bl   [40000,128]@[128,128]
// Wl cached in LDS; each thread computes 4 rows x 1 channel (4 FMA per LDS word)
// ---------------------------------------------------------------------------
#define HROWS 8
__global__ __launch_bounds__(256) void node_linear_kernel(
    const float* __restrict__ x, const float* __restrict__ Wl,
    const float* __restrict__ bl, float* __restrict__ h) {
  __shared__ float sW[IN_CH * OUT_CH];  // 64 KB
  __shared__ float sX[HROWS * IN_CH];   // 4 KB
  const int t = threadIdx.x;
  const int rbase = blockIdx.x * HROWS;

  const float4* Wl4 = (const float4*)Wl;
  float4* sW4 = (float4*)sW;
  for (int i = t; i < (IN_CH * OUT_CH) / 4; i += 256) sW4[i] = Wl4[i];
  const float4* x4 = (const float4*)(x + rbase * IN_CH);
  float4* sX4 = (float4*)sX;
  sX4[t] = x4[t];  // HROWS*IN_CH/4 == 256 exactly
  __syncthreads();

  const int c = t & 127;
  const int r0 = (t >> 7) * 4;  // rows r0..r0+3
  float b = bl[c];
  float a0 = b, a1 = b, a2 = b, a3 = b;
#pragma unroll 4
  for (int k = 0; k < IN_CH; ++k) {
    float wv = sW[k * OUT_CH + c];
    a0 += sX[(r0 + 0) * IN_CH + k] * wv;
    a1 += sX[(r0 + 1) * IN_CH + k] * wv;
    a2 += sX[(r0 + 2) * IN_CH + k] * wv;
    a3 += sX[(r0 + 3) * IN_CH + k] * wv;
  }
  h[(rbase + r0 + 0) * OUT_CH + c] = a0;
  h[(rbase + r0 + 1) * OUT_CH + c] = a1;
  h[(rbase + r0 + 2) * OUT_CH + c] = a2;
  h[(rbase + r0 + 3) * OUT_CH + c] = a3;
}

// ---------------------------------------------------------------------------
// Fused edge kernel
// ---------------------------------------------------------------------------
__global__ __launch_bounds__(256, 2) void cfconv_edge_kernel(
    const int* __restrict__ eidx,   // [2*E]: rows then cols
    const float* __restrict__ rbf,  // [E, 64]
    const float* __restrict__ W1, const float* __restrict__ b1,
    const float* __restrict__ W2, const float* __restrict__ b2,
    const float* __restrict__ h,  // [N,128] fp32
    float* __restrict__ out)      // [N,128] fp32 (pre-zeroed)
{
  __shared__ __align__(16) unsigned short sW1T[OUT_CH * W1_STR];  // 18432 B
  __shared__ __align__(16) unsigned short sW2T[OUT_CH * W2_STR];  // 34816 B
  __shared__ __align__(16) unsigned short sRbf[TILE_M * RBF_STR]; //  9216 B
  __shared__ __align__(16) unsigned short sT[TILE_M * T_STR];     // 17408 B
  __shared__ int sRow[TILE_M];
  __shared__ int sCol[TILE_M];
  // total ~80.4 KB -> 2 blocks/CU

  const int t = threadIdx.x;
  const int lane = t & 63;
  const int l31 = lane & 31;
  const int lhalf = lane >> 5;  // 0/1
  const int wv = t >> 6;        // wave 0..3, owns channels [wv*32, wv*32+32)

  // ---- stage W1^T (n-major, k-contig) and W2^T into LDS as bf16 ----
  {
    const int k = t >> 2;             // 0..63
    const int c0 = (t & 3) * 32;
#pragma unroll
    for (int i = 0; i < 8; ++i) {
      float4 v = *(const float4*)(W1 + k * OUT_CH + c0 + 4 * i);
      sW1T[(c0 + 4 * i + 0) * W1_STR + k] = f2bf(v.x);
      sW1T[(c0 + 4 * i + 1) * W1_STR + k] = f2bf(v.y);
      sW1T[(c0 + 4 * i + 2) * W1_STR + k] = f2bf(v.z);
      sW1T[(c0 + 4 * i + 3) * W1_STR + k] = f2bf(v.w);
    }
    const int k2 = t >> 1;            // 0..127
    const int d0 = (t & 1) * 64;
#pragma unroll
    for (int i = 0; i < 16; ++i) {
      float4 v = *(const float4*)(W2 + k2 * OUT_CH + d0 + 4 * i);
      sW2T[(d0 + 4 * i + 0) * W2_STR + k2] = f2bf(v.x);
      sW2T[(d0 + 4 * i + 1) * W2_STR + k2] = f2bf(v.y);
      sW2T[(d0 + 4 * i + 2) * W2_STR + k2] = f2bf(v.z);
      sW2T[(d0 + 4 * i + 3) * W2_STR + k2] = f2bf(v.w);
    }
  }
  __syncthreads();

  // ---- W fragments -> registers (tile-invariant). B layout: n=lane&31,
  //      k = kkbase + 8*(lane>>5) + j ----
  const int nbase = wv * 32 + l31;  // this lane's output channel
  bf16x8 B1[4], B2[8];
#pragma unroll
  for (int kk = 0; kk < 4; ++kk)
    B1[kk] = *(const bf16x8*)&sW1T[nbase * W1_STR + kk * 16 + lhalf * 8];
#pragma unroll
  for (int kk = 0; kk < 8; ++kk)
    B2[kk] = *(const bf16x8*)&sW2T[nbase * W2_STR + kk * 16 + lhalf * 8];
  const float b1v = b1[nbase];
  const float b2v = b2[nbase];

  const int* rowI = eidx;
  const int* colI = eidx + N_EDGES;

  for (int tile = blockIdx.x; tile < NTILES; tile += gridDim.x) {
    const int ebase = tile * TILE_M;
    __syncthreads();  // protect sRbf/sT/sRow/sCol from previous iteration

    // ---- stage rbf tile (bf16) + edge indices ----
    {
      const int m = t >> 2;
      const int kq = (t & 3) * 16;
      const float* src = rbf + (ebase + m) * NUM_RBF + kq;
#pragma unroll
      for (int i = 0; i < 4; ++i) {
        float4 v = *(const float4*)(src + 4 * i);
        ushort4 p;
        p.x = f2bf(v.x); p.y = f2bf(v.y); p.z = f2bf(v.z); p.w = f2bf(v.w);
        *(ushort4*)&sRbf[m * RBF_STR + kq + 4 * i] = p;
      }
      if (t < TILE_M) sRow[t] = rowI[ebase + t];
      else if (t < 2 * TILE_M) sCol[t - TILE_M] = colI[ebase + t - TILE_M];
    }
    __syncthreads();

    // ---- GEMM1: T = relu(rbf @ W1 + b1), this wave's 32 channels ----
#pragma unroll
    for (int mt = 0; mt < 2; ++mt) {
      f32x16 acc = {0.f, 0.f, 0.f, 0.f, 0.f, 0.f, 0.f, 0.f,
                    0.f, 0.f, 0.f, 0.f, 0.f, 0.f, 0.f, 0.f};
#pragma unroll
      for (int kk = 0; kk < 4; ++kk) {
        bf16x8 A = *(const bf16x8*)&sRbf[(mt * 32 + l31) * RBF_STR + kk * 16 + lhalf * 8];
        acc = __builtin_amdgcn_mfma_f32_32x32x16_bf16(A, B1[kk], acc, 0, 0, 0);
      }
      // C/D layout: col=lane&31, row=(r&3)+8*(r>>2)+4*(lane>>5)
#pragma unroll
      for (int r = 0; r < 16; ++r) {
        const int rowm = (r & 3) + 8 * (r >> 2) + 4 * lhalf;
        float v = acc[r] + b1v;
        v = v > 0.f ? v : 0.f;
        sT[(mt * 32 + rowm) * T_STR + nbase] = f2bf(v);
      }
    }
    __syncthreads();  // sT written across waves; GEMM2 reads all k

    // ---- GEMM2 + gather/modulate/scatter epilogue ----
#pragma unroll
    for (int mt = 0; mt < 2; ++mt) {
      f32x16 acc = {0.f, 0.f, 0.f, 0.f, 0.f, 0.f, 0.f, 0.f,
                    0.f, 0.f, 0.f, 0.f, 0.f, 0.f, 0.f, 0.f};
#pragma unroll
      for (int kk = 0; kk < 8; ++kk) {
        bf16x8 A = *(const bf16x8*)&sT[(mt * 32 + l31) * T_STR + kk * 16 + lhalf * 8];
        acc = __builtin_amdgcn_mfma_f32_32x32x16_bf16(A, B2[kk], acc, 0, 0, 0);
      }
#pragma unroll
      for (int r = 0; r < 16; ++r) {
        const int rowm = mt * 32 + (r & 3) + 8 * (r >> 2) + 4 * lhalf;
        const float wval = acc[r] + b2v;
        const int src = sCol[rowm];   // broadcast across 32 lanes
        const int dst = sRow[rowm];
        const float msg = h[src * OUT_CH + nbase] * wval;
        atomicAdd(&out[dst * OUT_CH + nbase], msg);
      }
    }
  }
}

extern "C" void kernel_launch(void* const* d_in, const int* in_sizes, int n_in,
                              void* d_out, int out_size, void* d_ws, size_t ws_size,
                              hipStream_t stream) {
  const float* x    = (const float*)d_in[0];
  const int*   eidx = (const int*)d_in[1];
  const float* rbf  = (const float*)d_in[2];
  const float* W1   = (const float*)d_in[3];
  const float* b1   = (const float*)d_in[4];
  const float* W2   = (const float*)d_in[5];
  const float* b2   = (const float*)d_in[6];
  const float* Wl   = (const float*)d_in[7];
  const float* bl   = (const float*)d_in[8];
  float* out = (float*)d_out;
  float* h = (float*)d_ws;  // 40000*128*4 = 20.48 MB scratch

  hipMemsetAsync(d_out, 0, (size_t)N_NODES * OUT_CH * sizeof(float), stream);
  node_linear_kernel<<<N_NODES / HROWS, 256, 0, stream>>>(x, Wl, bl, h);
  cfconv_edge_kernel<<<1024, 256, 0, stream>>>(eidx, rbf, W1, b1, W2, b2, h, out);
}